// Round 7
// baseline (29.036 us; speedup 1.0000x reference)
//
#include <hip/hip_runtime.h>

// Problem: B=4096, N=16, E=512. Outputs: aggregated (B,E) then weights (B,N), f32.
//
// task_anchor @ v_t is a per-b constant across the softmax axis -> dead input
// (softmax shift invariance). Traffic floor: 134.2 MB read + 8.9 MB write.
//
// R7 structure: 1024 blocks x 4 waves; each block handles 4 consecutive b's.
// Per b: wave w owns e-slice [128w,128w+128), lane owns f32x2 per row ->
// 32-VGPR tile (R4-verified). Double-buffered tiles TA/TB: prefetch b+1's
// tile while computing b, so every wave keeps ~16 global loads in flight
// through its compute phase (kills load/compute convoys). Barriers are raw
// s_barrier + lgkmcnt-only waits: cross-wave lds_s traffic needs DS ordering
// only, so prefetch vmcnt stays outstanding across barriers (avoids the
// __syncthreads vmcnt(0) drain).

#define NB 4096
#define NEXP 16
#define EDIM 512
#define BPB 4

typedef float f32x2 __attribute__((ext_vector_type(2)));

__device__ __forceinline__ void load_tile(f32x2 (&T)[NEXP],
                                          const float* __restrict__ expert,
                                          int b, int eoff) {
    const float* row = expert + (size_t)b * (NEXP * EDIM) + eoff;
#pragma unroll
    for (int n = 0; n < NEXP; ++n)
        T[n] = *(const f32x2*)(row + n * EDIM);
}

__device__ __forceinline__ void process_b(const f32x2 (&T)[NEXP], f32x2 ve,
                                          int wave, int lane, int b, int eoff,
                                          float (*lds_s)[4],
                                          float* __restrict__ out_agg,
                                          float* __restrict__ out_w) {
    // Per-lane partial dots (waits only on T's own loads: vmcnt(prefetch))
    float cur[NEXP];
#pragma unroll
    for (int n = 0; n < NEXP; ++n)
        cur[n] = T[n].x * ve.x + T[n].y * ve.y;

    // Multi-value butterfly: 16 partials over 64 lanes in 17 shuffles
    // (verified R4). Lane ends owning score rev4(lane&15).
    float t8[8];
    {
        const bool hi = (lane & 1) != 0;
#pragma unroll
        for (int j = 0; j < 8; ++j) {
            const float send = hi ? cur[j] : cur[j + 8];
            const float keep = hi ? cur[j + 8] : cur[j];
            t8[j] = keep + __shfl_xor(send, 1, 64);
        }
    }
    float t4[4];
    {
        const bool hi = (lane & 2) != 0;
#pragma unroll
        for (int j = 0; j < 4; ++j) {
            const float send = hi ? t8[j] : t8[j + 4];
            const float keep = hi ? t8[j + 4] : t8[j];
            t4[j] = keep + __shfl_xor(send, 2, 64);
        }
    }
    float t2[2];
    {
        const bool hi = (lane & 4) != 0;
#pragma unroll
        for (int j = 0; j < 2; ++j) {
            const float send = hi ? t4[j] : t4[j + 2];
            const float keep = hi ? t4[j + 2] : t4[j];
            t2[j] = keep + __shfl_xor(send, 4, 64);
        }
    }
    float t1;
    {
        const bool hi = (lane & 8) != 0;
        const float send = hi ? t2[0] : t2[1];
        const float keep = hi ? t2[1] : t2[0];
        t1 = keep + __shfl_xor(send, 8, 64);
    }
    t1 += __shfl_xor(t1, 16, 64);
    t1 += __shfl_xor(t1, 32, 64);

    // Cross-wave combine. lgkmcnt-only barrier: prefetched GLOBAL loads
    // (vmcnt) stay in flight across it.
    if (lane < 16) {
        const int idx = ((lane & 1) << 3) | ((lane & 2) << 1) |
                        ((lane & 4) >> 1) | ((lane & 8) >> 3);
        lds_s[idx][wave] = t1;
    }
    asm volatile("s_waitcnt lgkmcnt(0)" ::: "memory");
    __builtin_amdgcn_s_barrier();
    asm volatile("" ::: "memory");

    float s[NEXP];
#pragma unroll
    for (int n = 0; n < NEXP; ++n)
        s[n] = (lds_s[n][0] + lds_s[n][1]) + (lds_s[n][2] + lds_s[n][3]);

    // Softmax over 16 scores (redundant per thread, no divergence)
    float mx = s[0];
#pragma unroll
    for (int n = 1; n < NEXP; ++n) mx = fmaxf(mx, s[n]);
    float w[NEXP];
    float sum = 0.0f;
#pragma unroll
    for (int n = 0; n < NEXP; ++n) {
        w[n] = __expf(s[n] - mx);
        sum += w[n];
    }
    const float inv = 1.0f / sum;
#pragma unroll
    for (int n = 0; n < NEXP; ++n) w[n] *= inv;

    // Aggregation from the register tile (no global re-read)
    f32x2 acc = {0.f, 0.f};
#pragma unroll
    for (int n = 0; n < NEXP; ++n) {
        acc.x += w[n] * T[n].x;
        acc.y += w[n] * T[n].y;
    }
    *(f32x2*)(out_agg + (size_t)b * EDIM + eoff) = acc;

    if (wave == 0) {
        float myw = w[0];
#pragma unroll
        for (int n = 1; n < NEXP; ++n) myw = (lane == n) ? w[n] : myw;
        if (lane < NEXP) out_w[(size_t)b * NEXP + lane] = myw;
    }

    // Protect lds_s before next iteration's writes; again lgkmcnt-only.
    asm volatile("s_waitcnt lgkmcnt(0)" ::: "memory");
    __builtin_amdgcn_s_barrier();
    asm volatile("" ::: "memory");
}

__global__ __launch_bounds__(256, 4) void meta_attn_kernel(
    const float* __restrict__ expert,   // [B, 16, 512]
    const float* __restrict__ v,        // [640, 1]
    float* __restrict__ out_agg,        // [B, 512]
    float* __restrict__ out_w)          // [B, 16]
{
    const int wave = threadIdx.x >> 6;
    const int lane = threadIdx.x & 63;
    const int b0 = blockIdx.x * BPB;
    const int eoff = 128 * wave + 2 * lane;

    __shared__ float lds_s[NEXP][4];

    const f32x2 ve = *(const f32x2*)(v + eoff);

    f32x2 TA[NEXP], TB[NEXP];   // ping-pong register tiles, static indexing

    load_tile(TA, expert, b0 + 0, eoff);
    load_tile(TB, expert, b0 + 1, eoff);            // prefetch b1
    process_b(TA, ve, wave, lane, b0 + 0, eoff, lds_s, out_agg, out_w);
    load_tile(TA, expert, b0 + 2, eoff);            // prefetch b2
    process_b(TB, ve, wave, lane, b0 + 1, eoff, lds_s, out_agg, out_w);
    load_tile(TB, expert, b0 + 3, eoff);            // prefetch b3
    process_b(TA, ve, wave, lane, b0 + 2, eoff, lds_s, out_agg, out_w);
    process_b(TB, ve, wave, lane, b0 + 3, eoff, lds_s, out_agg, out_w);
}

extern "C" void kernel_launch(void* const* d_in, const int* in_sizes, int n_in,
                              void* d_out, int out_size, void* d_ws, size_t ws_size,
                              hipStream_t stream) {
    // d_in: 0=scene_repr (unused), 1=task_anchor (unused), 2=expert_reprs, 3=v
    const float* expert = (const float*)d_in[2];
    const float* v      = (const float*)d_in[3];
    float* out_agg = (float*)d_out;
    float* out_w   = (float*)d_out + (size_t)NB * EDIM;

    meta_attn_kernel<<<dim3(NB / BPB), dim3(256), 0, stream>>>(expert, v, out_agg, out_w);
}

// Round 8
// 26.012 us; speedup vs baseline: 1.1163x; 1.1163x over previous
//
#include <hip/hip_runtime.h>

// Problem: B=4096, N=16, E=512. Outputs: aggregated (B,E) then weights (B,N), f32.
//
// task_anchor @ v_t is a per-b constant across the softmax axis -> dead input
// (softmax shift invariance). Traffic floor: 134.2 MB read + 8.9 MB write.
//
// R8 = R4 (best, 26.39 us) + VGPR diet to cross the 64-VGPR occupancy
// breakpoint (8 waves/SIMD instead of 4, per m69):
//  - fused exp+aggregation: acc += exp(s[n]-mx)*tile[n] unnormalized,
//    scaled by 1/sum at the end -> no persistent w[16] array, one fewer pass
//  - __launch_bounds__(256,8) caps the allocator at 64 VGPRs
//  - nontemporal expert loads / output stores (streaming, use-once)
// Persistent state: tile 32 + s 16 + ~10 misc ~= 58 VGPRs.

#define NB 4096
#define NEXP 16
#define EDIM 512

typedef float f32x2 __attribute__((ext_vector_type(2)));

__global__ __launch_bounds__(256, 8) void meta_attn_kernel(
    const float* __restrict__ expert,   // [B, 16, 512]
    const float* __restrict__ v,        // [640, 1]; v_e = v[0:512]
    float* __restrict__ out_agg,        // [B, 512]
    float* __restrict__ out_w)          // [B, 16]
{
    const int wave = threadIdx.x >> 6;
    const int lane = threadIdx.x & 63;
    const int b = blockIdx.x;

    const int eoff = 128 * wave + 2 * lane;            // this thread's e-offset
    const float* row = expert + (size_t)b * (NEXP * EDIM) + eoff;

    const f32x2 ve = *(const f32x2*)(v + eoff);

    // Register tile: this thread's float2 of every row (32 VGPRs)
    f32x2 tile[NEXP];
#pragma unroll
    for (int n = 0; n < NEXP; ++n)
        tile[n] = __builtin_nontemporal_load((const f32x2*)(row + n * EDIM));

    // Per-lane partial dots
    float cur[NEXP];
#pragma unroll
    for (int n = 0; n < NEXP; ++n)
        cur[n] = tile[n].x * ve.x + tile[n].y * ve.y;

    // Multi-value butterfly: 16 partials over 64 lanes in 17 shuffles
    // (verified R4). Lane ends owning score rev4(lane&15).
    float t8[8];
    {
        const bool hi = (lane & 1) != 0;
#pragma unroll
        for (int j = 0; j < 8; ++j) {
            const float send = hi ? cur[j] : cur[j + 8];
            const float keep = hi ? cur[j + 8] : cur[j];
            t8[j] = keep + __shfl_xor(send, 1, 64);
        }
    }
    float t4[4];
    {
        const bool hi = (lane & 2) != 0;
#pragma unroll
        for (int j = 0; j < 4; ++j) {
            const float send = hi ? t8[j] : t8[j + 4];
            const float keep = hi ? t8[j + 4] : t8[j];
            t4[j] = keep + __shfl_xor(send, 2, 64);
        }
    }
    float t2[2];
    {
        const bool hi = (lane & 4) != 0;
#pragma unroll
        for (int j = 0; j < 2; ++j) {
            const float send = hi ? t4[j] : t4[j + 2];
            const float keep = hi ? t4[j + 2] : t4[j];
            t2[j] = keep + __shfl_xor(send, 4, 64);
        }
    }
    float t1;
    {
        const bool hi = (lane & 8) != 0;
        const float send = hi ? t2[0] : t2[1];
        const float keep = hi ? t2[1] : t2[0];
        t1 = keep + __shfl_xor(send, 8, 64);
    }
    t1 += __shfl_xor(t1, 16, 64);
    t1 += __shfl_xor(t1, 32, 64);

    // Cross-wave combine via 256 B LDS
    __shared__ float lds_s[NEXP][4];
    if (lane < 16) {
        const int idx = ((lane & 1) << 3) | ((lane & 2) << 1) |
                        ((lane & 4) >> 1) | ((lane & 8) >> 3);
        lds_s[idx][wave] = t1;
    }
    __syncthreads();

    float s[NEXP];
#pragma unroll
    for (int n = 0; n < NEXP; ++n)
        s[n] = (lds_s[n][0] + lds_s[n][1]) + (lds_s[n][2] + lds_s[n][3]);

    // Max for numerical stability
    float mx = s[0];
#pragma unroll
    for (int n = 1; n < NEXP; ++n) mx = fmaxf(mx, s[n]);

    // Fused exp + aggregation: unnormalized accumulate, scale at end.
    // (no persistent w[16] array -> fits the 64-VGPR occupancy breakpoint)
    f32x2 acc = {0.f, 0.f};
    float sum = 0.0f;
    float myw = 0.0f;           // wave0 lane n keeps exp(s[n]-mx)
#pragma unroll
    for (int n = 0; n < NEXP; ++n) {
        const float u = __expf(s[n] - mx);
        sum += u;
        acc.x += u * tile[n].x;
        acc.y += u * tile[n].y;
        myw = (lane == n) ? u : myw;
    }
    const float inv = 1.0f / sum;
    acc.x *= inv;
    acc.y *= inv;

    __builtin_nontemporal_store(acc, (f32x2*)(out_agg + (size_t)b * EDIM + eoff));

    if (wave == 0 && lane < NEXP)
        out_w[(size_t)b * NEXP + lane] = myw * inv;
}

extern "C" void kernel_launch(void* const* d_in, const int* in_sizes, int n_in,
                              void* d_out, int out_size, void* d_ws, size_t ws_size,
                              hipStream_t stream) {
    // d_in: 0=scene_repr (unused), 1=task_anchor (unused), 2=expert_reprs, 3=v
    const float* expert = (const float*)d_in[2];
    const float* v      = (const float*)d_in[3];
    float* out_agg = (float*)d_out;
    float* out_w   = (float*)d_out + (size_t)NB * EDIM;

    meta_attn_kernel<<<dim3(NB), dim3(256), 0, stream>>>(expert, v, out_agg, out_w);
}